// Round 1
// baseline (1913.342 us; speedup 1.0000x reference)
//
#include <hip/hip_runtime.h>
#include <stdint.h>

#define TILE 128
#define BK 32

typedef float f32x4 __attribute__((ext_vector_type(4)));
typedef const __attribute__((address_space(1))) void* gp1_t;
typedef __attribute__((address_space(3))) void* lp3_t;

__device__ __forceinline__ void gload_lds16(const void* g, void* l) {
  __builtin_amdgcn_global_load_lds((gp1_t)g, (lp3_t)l, 16, 0, 0);
}

__device__ __forceinline__ uint32_t pack4_fp8(float a, float b, float c, float d) {
  a = fminf(fmaxf(a, -448.f), 448.f);
  b = fminf(fmaxf(b, -448.f), 448.f);
  c = fminf(fmaxf(c, -448.f), 448.f);
  d = fminf(fmaxf(d, -448.f), 448.f);
  uint32_t v = 0;
  v = __builtin_amdgcn_cvt_pk_fp8_f32(a, b, v, false);  // bytes 0,1
  v = __builtin_amdgcn_cvt_pk_fp8_f32(c, d, v, true);   // bytes 2,3
  return v;
}

// Each thread converts 16 consecutive floats -> 16 fp8 bytes (one uint4 store).
__global__ __launch_bounds__(256) void quant_fp8(const float* __restrict__ in,
                                                 uint4* __restrict__ out) {
  size_t t = (size_t)blockIdx.x * 256 + threadIdx.x;
  const float4* in4 = (const float4*)in;
  float4 v0 = in4[t * 4 + 0];
  float4 v1 = in4[t * 4 + 1];
  float4 v2 = in4[t * 4 + 2];
  float4 v3 = in4[t * 4 + 3];
  uint4 r;
  r.x = pack4_fp8(v0.x, v0.y, v0.z, v0.w);
  r.y = pack4_fp8(v1.x, v1.y, v1.z, v1.w);
  r.z = pack4_fp8(v2.x, v2.y, v2.z, v2.w);
  r.w = pack4_fp8(v3.x, v3.y, v3.z, v3.w);
  out[t] = r;
}

// C[M,N] = A[M,K](fp8) * B[N,K](fp8)^T + bias, fp32 accumulate.
// m97-style: 128x128 tile / 256 threads, BK=32, global_load_lds(16B) staging,
// 2x2 waves each computing 64x64 via 4x4 of mfma_f32_16x16x32_fp8_fp8.
__global__ __launch_bounds__(256) void gemm_fp8(const uint8_t* __restrict__ A,
                                                const uint8_t* __restrict__ B,
                                                const float* __restrict__ bias,
                                                float* __restrict__ C,
                                                int M, int N, int K) {
  __shared__ uint8_t As[TILE * BK];
  __shared__ uint8_t Bs[TILE * BK];

  // Grouped swizzle: 16 m-tiles per group, m varies fastest -> per-XCD L2 reuse.
  const int num_n = N / TILE;
  const int GM = 16;
  int bid = blockIdx.x;
  int per_group = GM * num_n;
  int group = bid / per_group;
  int rem = bid - group * per_group;
  int tile_m = group * GM + (rem % GM);
  int tile_n = rem / GM;

  const int tid = threadIdx.x;
  const int wave = tid >> 6;
  const int lane = tid & 63;

  const size_t m0 = (size_t)tile_m * TILE;
  const size_t n0 = (size_t)tile_n * TILE;

  // Staging: thread t loads 16B; row = t/2, byte-offset (t&1)*16. LDS dst is
  // wave-uniform base + lane*16 (global_load_lds constraint) == As + t*16.
  const int srow = tid >> 1;
  const int scol = (tid & 1) * 16;
  const uint8_t* agp = A + (m0 + srow) * (size_t)K + scol;
  const uint8_t* bgp = B + (n0 + srow) * (size_t)K + scol;
  uint8_t* alds = As + wave * 1024;
  uint8_t* blds = Bs + wave * 1024;

  const int wm = wave & 1;   // wave tile: (wm*64, wn*64)
  const int wn = wave >> 1;
  const int lm = lane & 15;
  const int quad = lane >> 4;

  f32x4 acc[4][4] = {};

  int a_off[4], b_off[4];
#pragma unroll
  for (int i = 0; i < 4; ++i) {
    a_off[i] = (wm * 64 + i * 16 + lm) * BK + quad * 8;
    b_off[i] = (wn * 64 + i * 16 + lm) * BK + quad * 8;
  }

  for (int kt = 0; kt < K; kt += BK) {
    gload_lds16(agp + kt, alds);
    gload_lds16(bgp + kt, blds);
    __syncthreads();  // compiler drains vmcnt before s_barrier
    long af[4], bf[4];
#pragma unroll
    for (int i = 0; i < 4; ++i) af[i] = *(const long*)(As + a_off[i]);
#pragma unroll
    for (int j = 0; j < 4; ++j) bf[j] = *(const long*)(Bs + b_off[j]);
#pragma unroll
    for (int i = 0; i < 4; ++i)
#pragma unroll
      for (int j = 0; j < 4; ++j)
        acc[i][j] = __builtin_amdgcn_mfma_f32_16x16x32_fp8_fp8(af[i], bf[j], acc[i][j], 0, 0, 0);
    __syncthreads();  // protect LDS before next stage
  }

  // Epilogue: C/D layout col = lane&15, row = quad*4 + reg (m89-verified).
  const int row_base = (int)m0 + wm * 64 + quad * 4;
  const int col_base = (int)n0 + wn * 64 + lm;
#pragma unroll
  for (int j = 0; j < 4; ++j) {
    int col = col_base + j * 16;
    float bv = bias[col];
#pragma unroll
    for (int i = 0; i < 4; ++i) {
      int row = row_base + i * 16;
#pragma unroll
      for (int r = 0; r < 4; ++r) {
        __builtin_nontemporal_store(acc[i][j][r] + bv, C + (size_t)(row + r) * N + col);
      }
    }
  }
}

extern "C" void kernel_launch(void* const* d_in, const int* in_sizes, int n_in,
                              void* d_out, int out_size, void* d_ws, size_t ws_size,
                              hipStream_t stream) {
  const float* x = (const float*)d_in[0];
  const float* W = (const float*)d_in[1];
  const float* bias = (const float*)d_in[2];
  float* out = (float*)d_out;

  const int N = in_sizes[2];                 // 16384
  const int K = in_sizes[1] / N;             // 4096
  const int M = in_sizes[0] / K;             // 8192

  uint8_t* Xq = (uint8_t*)d_ws;
  uint8_t* Wq = Xq + (size_t)M * K;

  // fp32 -> fp8 e4m3fn (RNE, matches ml_dtypes), clamp +-448 per reference.
  {
    int blocks_x = (int)(((size_t)M * K) / (16 * 256));
    quant_fp8<<<blocks_x, 256, 0, stream>>>(x, (uint4*)Xq);
    int blocks_w = (int)(((size_t)N * K) / (16 * 256));
    quant_fp8<<<blocks_w, 256, 0, stream>>>(W, (uint4*)Wq);
  }

  int grid = (M / TILE) * (N / TILE);  // 64 * 128 = 8192
  gemm_fp8<<<grid, 256, 0, stream>>>(Xq, Wq, bias, out, M, N, K);
}